// Round 6
// baseline (2154.679 us; speedup 1.0000x reference)
//
#include <hip/hip_runtime.h>

#define B 4096
#define T 2048
#define H 64
#define NBATCH 16
#define NB (B / NBATCH)     // 256 blocks -> 1 per CU
#define NTHREADS 512        // 8 waves = 2 groups x 4 waves, independent sync

typedef __attribute__((ext_vector_type(8))) short short8;
typedef __attribute__((ext_vector_type(4))) float f32x4;

__device__ __forceinline__ float ex2(float x) { return __builtin_amdgcn_exp2f(x); }
__device__ __forceinline__ unsigned short f2bf(float f) {  // RNE f32->bf16
    unsigned u = __builtin_bit_cast(unsigned, f);
    u += 0x7fffu + ((u >> 16) & 1u);
    return (unsigned short)(u >> 16);
}
// Pack two f32 -> two bf16 (RNE) in one instruction.
__device__ __forceinline__ unsigned pk_bf16(float a, float b) {
    unsigned r;
    asm("v_cvt_pk_bf16_f32 %0, %1, %2" : "=v"(r) : "v"(a), "v"(b));
    return r;
}
__device__ __forceinline__ void lds_barrier() {
    asm volatile("s_waitcnt lgkmcnt(0)\n\ts_barrier" ::: "memory");
}
// Group-local barrier: 4 waves, monotone LDS counter. Release-add drains this
// wave's LDS writes (all lanes) before the count lands; acquire-poll orders
// subsequent reads. Counts are wave-uniform per group -> no deadlock.
__device__ __forceinline__ void gsync(unsigned* c, unsigned tgt, int lane) {
    if (lane == 0)
        __hip_atomic_fetch_add(c, 1u, __ATOMIC_RELEASE, __HIP_MEMORY_SCOPE_WORKGROUP);
    while (__hip_atomic_load(c, __ATOMIC_ACQUIRE, __HIP_MEMORY_SCOPE_WORKGROUP) < tgt) {}
}

// Fused LSTM cell update (verified r5): sigm(a)*tanh(b) = (1-v)/((1+p)(1+v)).
__device__ __forceinline__ void cellstep(const f32x4 z, float& cs, float& hs, bool act) {
    const float KE = -1.4426950408889634f;   // -1/ln2
    const float KT = -2.8853900817779268f;   // -2/ln2
    float pf = ex2(KE * z[1]);
    float f_ = __builtin_amdgcn_rcpf(1.0f + pf);
    float p0 = ex2(KE * z[0]);
    float v_ = ex2(KT * z[2]);
    float ig = (1.0f - v_) * __builtin_amdgcn_rcpf((1.0f + p0) * (1.0f + v_));
    float cn = __builtin_fmaf(f_, cs, ig);
    float cc = fminf(15.0f, fmaxf(-15.0f, cn));
    float s_ = ex2(KE * z[3]);
    float r_ = ex2(KT * cc);
    float hn = (1.0f - r_) * __builtin_amdgcn_rcpf((1.0f + s_) * (1.0f + r_));
    if (act) { cs = cn; hs = hn; }
}

// ---------------------------------------------------------------------------
// Encoder: 256 blocks x 512 threads. TWO independent groups per block
// (g = wave>>2): each group = 8 batches x 64 units, 4 waves, own flag-barrier.
// Wave k of a group owns units 16k..16k+15 as FOUR 16-row tiles:
//   tile t: units u_t(h) = 16k + 8*(t>>1) + 2h + (t&1), rows G_t(m) =
//   (m&3)*64 + 16k + 8*(t>>1) + 2*(m>>2) + (t&1).
// B cols = 8 batches x 2 replicas (col lo -> batch lo&7, broadcast LDS read).
// Lane (lo,hi) owns cells (batch lo&7, units 16k+8*(lo>>3)+2hi +{0,1}) —
// quad select by lo>>3 (tiles 0,1 vs 2,3). Adjacent units -> single b32
// pk write. Group 1 sleeps ~512cy at start to force anti-phase: one group's
// serial recurrence path (barrier+ds_read+MFMA+act latency, the measured
// ~430cy/step idle) is covered by the other group's issue.
// ---------------------------------------------------------------------------
extern "C" __global__ void __launch_bounds__(NTHREADS, 2)
enc_kernel(const float* __restrict__ padded, const int* __restrict__ seq_len,
           const float* __restrict__ Wih, const float* __restrict__ Whh,
           const float* __restrict__ bias,
           float* __restrict__ h_out, float* __restrict__ c_out)
{
    __shared__ unsigned short hX[2][2][8][72];   // [group][buf][batch][64(+pad)]
    __shared__ int slen[NBATCH];
    __shared__ unsigned cnt[2];

    const int tid = threadIdx.x;
    const int w = tid >> 6, L = tid & 63, lo = L & 15, hi = L >> 4;
    const int g = w >> 2, k = w & 3;
    const int b0 = blockIdx.x * NBATCH;
    const int cb = lo & 7;                      // batch within group
    const int unitL = 16 * k + 8 * (lo >> 3) + 2 * hi;   // lane's even unit

    // A-frags for 4 tiles x 2 k-halves
    short8 af[4][2];
    #pragma unroll
    for (int t4 = 0; t4 < 4; ++t4) {
        const int G = (lo & 3) * 64 + 16 * k + 8 * (t4 >> 1) + 2 * (lo >> 2) + (t4 & 1);
        #pragma unroll
        for (int kk = 0; kk < 2; ++kk) {
            const float* src = Whh + (long)G * H + kk * 32 + hi * 8;
            short8 f;
            #pragma unroll
            for (int j = 0; j < 8; ++j) f[j] = (short)f2bf(src[j]);
            af[t4][kk] = f;
        }
    }
    float b_g[4][4], wi_g[4][4];
    #pragma unroll
    for (int t4 = 0; t4 < 4; ++t4)
        #pragma unroll
        for (int r = 0; r < 4; ++r) {
            const int G2 = r * 64 + 16 * k + 8 * (t4 >> 1) + 2 * hi + (t4 & 1);
            b_g[t4][r] = bias[G2];
            wi_g[t4][r] = Wih[G2];
        }

    for (int idx = tid; idx < 2 * 2 * 8 * 72; idx += NTHREADS)
        ((unsigned short*)hX)[idx] = 0;
    if (tid < NBATCH) slen[tid] = seq_len[b0 + tid];
    if (tid < 2) cnt[tid] = 0;
    lds_barrier();
    if (g == 1) __builtin_amdgcn_s_sleep(8);    // ~512cy anti-phase offset

    int maxlen = 1;
    #pragma unroll
    for (int i = 0; i < 8; ++i) maxlen = max(maxlen, slen[g * 8 + i]);
    const int len_lo = slen[g * 8 + cb];

    const float* xrow = padded + (long)(b0 + g * 8 + cb) * T;
    f32x4 xc = *(const f32x4*)(xrow);
    f32x4 xn = *(const f32x4*)(xrow + 4);

    float csA = 0.f, hsA = 0.f, csB = 0.f, hsB = 0.f;
    unsigned tgt = 0;

#define ESTEP(P, XI)                                                          \
    {                                                                         \
        const float x = xc[XI];                                               \
        short8 hb0 = *(const short8*)&hX[g][P][cb][hi * 8];                   \
        short8 hb1 = *(const short8*)&hX[g][P][cb][32 + hi * 8];              \
        f32x4 q0 = {b_g[0][0] + wi_g[0][0] * x, b_g[0][1] + wi_g[0][1] * x,   \
                    b_g[0][2] + wi_g[0][2] * x, b_g[0][3] + wi_g[0][3] * x};  \
        f32x4 q1 = {b_g[1][0] + wi_g[1][0] * x, b_g[1][1] + wi_g[1][1] * x,   \
                    b_g[1][2] + wi_g[1][2] * x, b_g[1][3] + wi_g[1][3] * x};  \
        f32x4 q2 = {b_g[2][0] + wi_g[2][0] * x, b_g[2][1] + wi_g[2][1] * x,   \
                    b_g[2][2] + wi_g[2][2] * x, b_g[2][3] + wi_g[2][3] * x};  \
        f32x4 q3 = {b_g[3][0] + wi_g[3][0] * x, b_g[3][1] + wi_g[3][1] * x,   \
                    b_g[3][2] + wi_g[3][2] * x, b_g[3][3] + wi_g[3][3] * x};  \
        q0 = __builtin_amdgcn_mfma_f32_16x16x32_bf16(af[0][0], hb0, q0, 0,0,0); \
        q1 = __builtin_amdgcn_mfma_f32_16x16x32_bf16(af[1][0], hb0, q1, 0,0,0); \
        q2 = __builtin_amdgcn_mfma_f32_16x16x32_bf16(af[2][0], hb0, q2, 0,0,0); \
        q3 = __builtin_amdgcn_mfma_f32_16x16x32_bf16(af[3][0], hb0, q3, 0,0,0); \
        q0 = __builtin_amdgcn_mfma_f32_16x16x32_bf16(af[0][1], hb1, q0, 0,0,0); \
        q1 = __builtin_amdgcn_mfma_f32_16x16x32_bf16(af[1][1], hb1, q1, 0,0,0); \
        q2 = __builtin_amdgcn_mfma_f32_16x16x32_bf16(af[2][1], hb1, q2, 0,0,0); \
        q3 = __builtin_amdgcn_mfma_f32_16x16x32_bf16(af[3][1], hb1, q3, 0,0,0); \
        const bool rep = lo < 8;                                              \
        f32x4 zA = rep ? q0 : q2;                                             \
        f32x4 zB = rep ? q1 : q3;                                             \
        const bool act = (t + XI) < len_lo;                                   \
        cellstep(zA, csA, hsA, act);                                          \
        cellstep(zB, csB, hsB, act);                                          \
        *(unsigned*)&hX[g][(P) ^ 1][cb][unitL] = pk_bf16(hsA, hsB);           \
        tgt += 4; gsync(&cnt[g], tgt, L);                                     \
    }

    for (int t = 0; t < maxlen; t += 4) {
        int nb = t + 8; if (nb > T - 4) nb = T - 4;
        f32x4 xf = *(const f32x4*)(xrow + nb);   // 8-step-ahead prefetch
        ESTEP(0, 0) ESTEP(1, 1) ESTEP(0, 2) ESTEP(1, 3)
        xc = xn; xn = xf;
    }
#undef ESTEP

    *(float2*)&h_out[(long)(b0 + g * 8 + cb) * H + unitL] = make_float2(hsA, hsB);
    *(float2*)&c_out[(long)(b0 + g * 8 + cb) * H + unitL] = make_float2(csA, csB);
}

// ---------------------------------------------------------------------------
// Bottleneck + y0 correction term for the decoder's rank-1 fold.
// ---------------------------------------------------------------------------
extern "C" __global__ void __launch_bounds__(256)
mid_kernel(const float* __restrict__ h_enc,
           const float* __restrict__ eW, const float* __restrict__ eb,
           const float* __restrict__ dW, const float* __restrict__ db,
           const float* __restrict__ outW, const float* __restrict__ outb,
           float* __restrict__ hz_out, float* __restrict__ hd_out,
           float* __restrict__ y0c)
{
    int b = blockIdx.x * blockDim.x + threadIdx.x;
    if (b >= B) return;
    const float* h = h_enc + (long)b * H;
    float hz[3];
    #pragma unroll
    for (int j = 0; j < 3; ++j) {
        float s = eb[j];
        for (int kq = 0; kq < H; ++kq) s += h[kq] * eW[j*H + kq];
        hz[j] = 1.0f / (1.0f + __builtin_expf(-s));
        hz_out[b*3 + j] = hz[j];
    }
    float y0 = outb[0];
    for (int u = 0; u < H; ++u) {
        float hd = db[u] + hz[0]*dW[u*3] + hz[1]*dW[u*3+1] + hz[2]*dW[u*3+2];
        hd_out[(long)b*H + u] = hd;
        y0 += outW[u] * hd;
    }
    y0c[b] = y0;
}

// ---------------------------------------------------------------------------
// Decoder: rank-1 fold -> pure LSTM, same 2-group flag-barrier structure.
// y_{t-1} via 2 extra MFMAs rotating across the group's 4 waves (k==t&3),
// one step delayed. t=0 correction peeled.
// ---------------------------------------------------------------------------
extern "C" __global__ void __launch_bounds__(NTHREADS, 2)
dec_kernel(const float* __restrict__ hd, const float* __restrict__ c_in,
           const float* __restrict__ Wih, const float* __restrict__ Whh,
           const float* __restrict__ bias, const float* __restrict__ outW,
           const float* __restrict__ outb, const float* __restrict__ y0c,
           float* __restrict__ y_out)
{
    __shared__ unsigned short hX[2][2][8][72];
    __shared__ unsigned cnt[2];

    const int tid = threadIdx.x;
    const int w = tid >> 6, L = tid & 63, lo = L & 15, hi = L >> 4;
    const int g = w >> 2, k = w & 3;
    const int b0 = blockIdx.x * NBATCH;
    const int cb = lo & 7;
    const int unitL = 16 * k + 8 * (lo >> 3) + 2 * hi;

    short8 af[4][2];
    #pragma unroll
    for (int t4 = 0; t4 < 4; ++t4) {
        const int G = (lo & 3) * 64 + 16 * k + 8 * (t4 >> 1) + 2 * (lo >> 2) + (t4 & 1);
        const float wir = Wih[G];
        #pragma unroll
        for (int kk = 0; kk < 2; ++kk) {
            const float* src = Whh + (long)G * H + kk * 32 + hi * 8;
            const float* ow  = outW + kk * 32 + hi * 8;
            short8 f;
            #pragma unroll
            for (int j = 0; j < 8; ++j) f[j] = (short)f2bf(src[j] + wir * ow[j]);
            af[t4][kk] = f;
        }
    }
    const float outb_s = outb[0];
    const float y0 = y0c[b0 + g * 8 + cb];
    float zb[4][4];
    #pragma unroll
    for (int t4 = 0; t4 < 4; ++t4)
        #pragma unroll
        for (int r = 0; r < 4; ++r) {
            const int G2 = r * 64 + 16 * k + 8 * (t4 >> 1) + 2 * hi + (t4 & 1);
            zb[t4][r] = bias[G2] + Wih[G2] * outb_s;
        }
    float corrA[4], corrB[4];
    #pragma unroll
    for (int r = 0; r < 4; ++r) {
        corrA[r] = Wih[r * 64 + unitL] * y0;
        corrB[r] = Wih[r * 64 + unitL + 1] * y0;
    }

    short8 ya[2];   // y-extraction A-frag: row 0 = outW, rows 1..15 = 0
    #pragma unroll
    for (int kk = 0; kk < 2; ++kk) {
        short8 f = (short8)0;
        if (lo == 0)
            #pragma unroll
            for (int j = 0; j < 8; ++j) f[j] = (short)f2bf(outW[kk*32 + hi*8 + j]);
        ya[kk] = f;
    }

    for (int idx = tid; idx < NBATCH * 64; idx += NTHREADS) {
        int m = idx >> 6, col = idx & 63;
        hX[m >> 3][0][m & 7][col] = f2bf(hd[(long)(b0 + m) * H + col]);
    }
    if (tid < 2) cnt[tid] = 0;
    float2 c2 = *(const float2*)&c_in[(long)(b0 + g * 8 + cb) * H + unitL];
    float csA = c2.x, csB = c2.y, hsA = 0.f, hsB = 0.f;
    lds_barrier();
    if (g == 1) __builtin_amdgcn_s_sleep(8);
    unsigned tgt = 0;

#define DSTEP(P, CORR, TT)                                                    \
    {                                                                         \
        short8 hb0 = *(const short8*)&hX[g][P][cb][hi * 8];                   \
        short8 hb1 = *(const short8*)&hX[g][P][cb][32 + hi * 8];              \
        f32x4 q0 = {zb[0][0], zb[0][1], zb[0][2], zb[0][3]};                  \
        f32x4 q1 = {zb[1][0], zb[1][1], zb[1][2], zb[1][3]};                  \
        f32x4 q2 = {zb[2][0], zb[2][1], zb[2][2], zb[2][3]};                  \
        f32x4 q3 = {zb[3][0], zb[3][1], zb[3][2], zb[3][3]};                  \
        q0 = __builtin_amdgcn_mfma_f32_16x16x32_bf16(af[0][0], hb0, q0, 0,0,0); \
        q1 = __builtin_amdgcn_mfma_f32_16x16x32_bf16(af[1][0], hb0, q1, 0,0,0); \
        q2 = __builtin_amdgcn_mfma_f32_16x16x32_bf16(af[2][0], hb0, q2, 0,0,0); \
        q3 = __builtin_amdgcn_mfma_f32_16x16x32_bf16(af[3][0], hb0, q3, 0,0,0); \
        q0 = __builtin_amdgcn_mfma_f32_16x16x32_bf16(af[0][1], hb1, q0, 0,0,0); \
        q1 = __builtin_amdgcn_mfma_f32_16x16x32_bf16(af[1][1], hb1, q1, 0,0,0); \
        q2 = __builtin_amdgcn_mfma_f32_16x16x32_bf16(af[2][1], hb1, q2, 0,0,0); \
        q3 = __builtin_amdgcn_mfma_f32_16x16x32_bf16(af[3][1], hb1, q3, 0,0,0); \
        if (k == ((TT) & 3)) {  /* y_{t-1} = outW.h_{t-1}+outb, rotated */    \
            f32x4 zy = {outb_s, outb_s, outb_s, outb_s};                      \
            zy = __builtin_amdgcn_mfma_f32_16x16x32_bf16(ya[0], hb0, zy, 0,0,0); \
            zy = __builtin_amdgcn_mfma_f32_16x16x32_bf16(ya[1], hb1, zy, 0,0,0); \
            if ((TT) > 0 && hi == 0 && lo < 8)                                \
                y_out[(long)(b0 + g * 8 + lo) * T + ((TT) - 1)] = zy[0];      \
        }                                                                     \
        const bool rep = lo < 8;                                              \
        f32x4 zA = rep ? q0 : q2;                                             \
        f32x4 zB = rep ? q1 : q3;                                             \
        if (CORR) {                                                           \
            _Pragma("unroll")                                                 \
            for (int r = 0; r < 4; ++r) { zA[r] -= corrA[r]; zB[r] -= corrB[r]; } \
        }                                                                     \
        cellstep(zA, csA, hsA, true);                                         \
        cellstep(zB, csB, hsB, true);                                         \
        *(unsigned*)&hX[g][(P) ^ 1][cb][unitL] = pk_bf16(hsA, hsB);           \
        tgt += 4; gsync(&cnt[g], tgt, L);                                     \
    }

    DSTEP(0, 1, 0) DSTEP(1, 0, 1) DSTEP(0, 0, 2) DSTEP(1, 0, 3)
    for (int t = 4; t < T; t += 4) {
        DSTEP(0, 0, t) DSTEP(1, 0, t + 1) DSTEP(0, 0, t + 2) DSTEP(1, 0, t + 3)
    }
#undef DSTEP

    if (k == 0) {       // final y_{T-1}: h_T is in buf 0; slot (T&3)==0
        short8 hb0 = *(const short8*)&hX[g][0][cb][hi * 8];
        short8 hb1 = *(const short8*)&hX[g][0][cb][32 + hi * 8];
        f32x4 zy = {outb_s, outb_s, outb_s, outb_s};
        zy = __builtin_amdgcn_mfma_f32_16x16x32_bf16(ya[0], hb0, zy, 0,0,0);
        zy = __builtin_amdgcn_mfma_f32_16x16x32_bf16(ya[1], hb1, zy, 0,0,0);
        if (hi == 0 && lo < 8) y_out[(long)(b0 + g * 8 + lo) * T + (T - 1)] = zy[0];
    }
}

// ---------------------------------------------------------------------------
extern "C" __global__ void __launch_bounds__(256)
loss_kernel(const float* __restrict__ padded, const float* __restrict__ y,
            const int* __restrict__ seq_len, float* __restrict__ acc2)
{
    const long n4 = (long)B * T / 4;
    long i0 = (long)(blockIdx.x * blockDim.x + threadIdx.x);
    long stride = (long)gridDim.x * blockDim.x;
    float s = 0.f, cntv = 0.f;
    for (long i = i0; i < n4; i += stride) {
        int b = (int)(i >> 9);                  // T/4 = 512
        int t = (int)(i & 511) * 4;
        int len = seq_len[b];
        f32x4 pv = *(const f32x4*)&padded[i * 4];
        f32x4 yv = *(const f32x4*)&y[i * 4];
        #pragma unroll
        for (int e = 0; e < 4; ++e)
            if (t + e < len) { float d = pv[e] - yv[e]; s += d * d; cntv += 1.0f; }
    }
    for (int m = 1; m < 64; m <<= 1) { s += __shfl_xor(s, m); cntv += __shfl_xor(cntv, m); }
    if ((threadIdx.x & 63) == 0) { atomicAdd(&acc2[0], s); atomicAdd(&acc2[1], cntv); }
}

extern "C" __global__ void fin_kernel(const float* __restrict__ acc2, float* __restrict__ out)
{
    out[0] = acc2[0] / acc2[1];
}

// ---------------------------------------------------------------------------
extern "C" void kernel_launch(void* const* d_in, const int* in_sizes, int n_in,
                              void* d_out, int out_size, void* d_ws, size_t ws_size,
                              hipStream_t stream)
{
    const float* padded = (const float*)d_in[0];
    const int*   seq    = (const int*)  d_in[1];
    const float* eWih   = (const float*)d_in[2];
    const float* eWhh   = (const float*)d_in[3];
    const float* eb     = (const float*)d_in[4];
    const float* elW    = (const float*)d_in[5];
    const float* elb    = (const float*)d_in[6];
    const float* dlW    = (const float*)d_in[7];
    const float* dlb    = (const float*)d_in[8];
    const float* dWih   = (const float*)d_in[9];
    const float* dWhh   = (const float*)d_in[10];
    const float* db     = (const float*)d_in[11];
    const float* outW   = (const float*)d_in[12];
    const float* outb   = (const float*)d_in[13];
    float* out = (float*)d_out;

    float* ws    = (float*)d_ws;
    float* h_enc = ws;
    float* c_enc = ws + (long)B * H;
    float* hd    = ws + 2L * B * H;
    float* y0c   = ws + 3L * B * H;
    float* acc2  = ws + 3L * B * H + B;

    float* out_pad = out + 1;
    float* out_y   = out + 1 + (long)B * T;
    float* out_hz  = out + 1 + 2L * (long)B * T;

    hipMemcpyAsync(out_pad, padded, (long)B * T * sizeof(float),
                   hipMemcpyDeviceToDevice, stream);
    hipMemsetAsync(acc2, 0, 2 * sizeof(float), stream);

    enc_kernel<<<NB, NTHREADS, 0, stream>>>(padded, seq, eWih, eWhh, eb, h_enc, c_enc);
    mid_kernel<<<B / 256, 256, 0, stream>>>(h_enc, elW, elb, dlW, dlb, outW, outb,
                                            out_hz, hd, y0c);
    dec_kernel<<<NB, NTHREADS, 0, stream>>>(hd, c_enc, dWih, dWhh, db, outW, outb, y0c, out_y);
    loss_kernel<<<1024, 256, 0, stream>>>(padded, out_y, seq, acc2);
    fin_kernel<<<1, 1, 0, stream>>>(acc2, out);
}